// Round 3
// baseline (528.147 us; speedup 1.0000x reference)
//
#include <hip/hip_runtime.h>
#include <hip/hip_bf16.h>
#include <math.h>

#define NTRI 69
#define NPAIR 21
#define NB 128
#define NGRP 64            // batch groups of 2 for sumsq partials
#define IN_LEN 864
#define MS_LEN 39744
#define W_CPLX 953856      // 24*MS_LEN
#define EPSV 1e-5f

typedef short short8 __attribute__((ext_vector_type(8)));
typedef float f32x4 __attribute__((ext_vector_type(4)));
typedef __hip_bfloat16 bf16;

struct CMeta { unsigned char l1[NTRI], l2[NTRI], lo[NTRI]; int cg_off[NTRI]; };
struct PMeta {
  int bb[NPAIR][6];     // B element base for (pair,l): boff[l]+tpos*576
  int gch[NPAIR][6];    // global channel base: ms_off[l]+tpos*576
  int cgo0[NPAIR];      // cg float offset of first triple of pair
  int K[6], mt[6];
};
struct GMeta { int aoff[6], boff[6], K[6], mt[6], w_off[6], ms_off[7], tb[7]; };

__constant__ double c_fac[18] = {
  1.0,1.0,2.0,6.0,24.0,120.0,720.0,5040.0,40320.0,362880.0,3628800.0,
  39916800.0,479001600.0,6227020800.0,87178291200.0,1307674368000.0,
  20922789888000.0,355687428096000.0 };

__device__ double cg_coef(int j1,int m1,int j2,int m2,int j,int m){
  if (m1+m2!=m) return 0.0;
  double pref = sqrt((2.0*j+1.0)*c_fac[j+j1-j2]*c_fac[j-j1+j2]*c_fac[j1+j2-j]/c_fac[j1+j2+j+1]);
  pref *= sqrt(c_fac[j+m]*c_fac[j-m]*c_fac[j1-m1]*c_fac[j1+m1]*c_fac[j2-m2]*c_fac[j2+m2]);
  int kmin = max(0, max(-(j-j2+m1), -(j-j1-m2)));
  int kmax = min(j1+j2-j, min(j1-m1, j2+m2));
  double s = 0.0;
  for (int k=kmin;k<=kmax;++k){
    double d = c_fac[k]*c_fac[j1+j2-j-k]*c_fac[j1-m1-k]*c_fac[j2+m2-k]*c_fac[j-j2+m1+k]*c_fac[j-j1-m2+k];
    s += ((k&1)? -1.0:1.0)/d;
  }
  return pref*s;
}

__global__ void k_init_cg(float* __restrict__ cg, CMeta cm){
  int tri = blockIdx.x;
  int l1=cm.l1[tri], l2=cm.l2[tri], l=cm.lo[tri];
  int n1=2*l1+1, nm=2*l+1;
  int n=nm*n1;
  for (int e=threadIdx.x; e<n; e+=blockDim.x){
    int mi=e/n1, xi=e-mi*n1;
    int m=mi-l, m1=xi-l1, m2=m-m1;
    float v=0.f;
    if (m2>=-l2 && m2<=l2) v=(float)cg_coef(l1,m1,l2,m2,l,m);
    cg[cm.cg_off[tri]+e]=v;
  }
}

// ---- pair-specialized middle computation ----
template<int L1,int L2>
__device__ __forceinline__ void mid_body(
    const float2* __restrict__ act, const float* __restrict__ cg,
    bf16* __restrict__ Bm, float* __restrict__ partial,
    const PMeta& pm, int pair, int ts, int b0, float* cgl)
{
  constexpr int N1=2*L1+1, N2=2*L2+1;
  constexpr int LMIN=L1-L2;
  constexpr int LMAX=(L1+L2<5)?(L1+L2):5;
  constexpr int NL=LMAX-LMIN+1;
  constexpr int ACCN=(LMAX+1)*(LMAX+1)-LMIN*LMIN;
  constexpr int CGTOT=ACCN*N1;
  for (int i=threadIdx.x;i<CGTOT;i+=192) cgl[i]=cg[pm.cgo0[pair]+i];
  __syncthreads();
  int t=ts/24, s=ts-24*t;
  int a1=24*L1*L1+t*N1;
  int a2=24*L2*L2+s*N2;
  int b=b0+(int)blockIdx.y*2;
  float ssum[NL];
  #pragma unroll
  for (int i=0;i<NL;++i) ssum[i]=0.f;
  #pragma unroll 1
  for (int bi=0;bi<2;++bi,++b){
    const float2* ab=act+(size_t)b*IN_LEN;
    float f1r[N1],f1i[N1],f2r[N2],f2i[N2];
    #pragma unroll
    for (int x=0;x<N1;++x){ float2 v=ab[a1+x]; f1r[x]=v.x; f1i[x]=v.y; }
    #pragma unroll
    for (int y=0;y<N2;++y){ float2 v=ab[a2+y]; f2r[y]=v.x; f2i[y]=v.y; }
    float accr[ACCN], acci[ACCN];
    #pragma unroll
    for (int i=0;i<ACCN;++i){ accr[i]=0.f; acci[i]=0.f; }
    #pragma unroll
    for (int x=0;x<N1;++x){
      #pragma unroll
      for (int y=0;y<N2;++y){
        float pr=f1r[x]*f2r[y]-f1i[x]*f2i[y];
        float pi=f1r[x]*f2i[y]+f1i[x]*f2r[y];
        const int ma=(x-L1)+(y-L2);
        #pragma unroll
        for (int l=LMIN;l<=LMAX;++l){
          if (ma>=-l && ma<=l){
            const int idx=l*l-LMIN*LMIN+(ma+l);
            float cv=cgl[idx*N1+x];
            accr[idx]+=cv*pr;
            acci[idx]+=cv*pi;
          }
        }
      }
    }
    int brel=b-b0;
    #pragma unroll
    for (int l=LMIN;l<=LMAX;++l){
      const int nm=2*l+1, base=l*l-LMIN*LMIN;
      int Kl=pm.K[l], mtl=pm.mt[l];
      size_t rowb=(size_t)pm.bb[pair][l]+(size_t)brel*nm*Kl+ts;
      float ssl=0.f;
      #pragma unroll
      for (int mi=0;mi<nm;++mi){
        float fr=accr[base+mi], fi=acci[base+mi];
        ssl+=fr*fr+fi*fi;
        Bm[rowb+(size_t)mi*Kl]=__float2bfloat16(fr);
        Bm[rowb+(size_t)mi*Kl+mtl]=__float2bfloat16(fi);
      }
      ssum[l-LMIN]+=ssl;
    }
  }
  int pg=(b0>>1)+blockIdx.y;
  #pragma unroll
  for (int l=LMIN;l<=LMAX;++l)
    partial[(size_t)pg*MS_LEN+pm.gch[pair][l]+ts]=ssum[l-LMIN];
}

__global__ __launch_bounds__(192)
void k_mid2(const float2* __restrict__ act, const float* __restrict__ cg,
            bf16* __restrict__ Bm, float* __restrict__ partial, PMeta pm, int b0){
  __shared__ float cgl[400];
  int pair = blockIdx.x/3;
  int seg  = blockIdx.x - pair*3;
  int ts = seg*192 + threadIdx.x;
  switch(pair){
    case 0:  mid_body<0,0>(act,cg,Bm,partial,pm,pair,ts,b0,cgl); break;
    case 1:  mid_body<1,0>(act,cg,Bm,partial,pm,pair,ts,b0,cgl); break;
    case 2:  mid_body<1,1>(act,cg,Bm,partial,pm,pair,ts,b0,cgl); break;
    case 3:  mid_body<2,0>(act,cg,Bm,partial,pm,pair,ts,b0,cgl); break;
    case 4:  mid_body<2,1>(act,cg,Bm,partial,pm,pair,ts,b0,cgl); break;
    case 5:  mid_body<2,2>(act,cg,Bm,partial,pm,pair,ts,b0,cgl); break;
    case 6:  mid_body<3,0>(act,cg,Bm,partial,pm,pair,ts,b0,cgl); break;
    case 7:  mid_body<3,1>(act,cg,Bm,partial,pm,pair,ts,b0,cgl); break;
    case 8:  mid_body<3,2>(act,cg,Bm,partial,pm,pair,ts,b0,cgl); break;
    case 9:  mid_body<3,3>(act,cg,Bm,partial,pm,pair,ts,b0,cgl); break;
    case 10: mid_body<4,0>(act,cg,Bm,partial,pm,pair,ts,b0,cgl); break;
    case 11: mid_body<4,1>(act,cg,Bm,partial,pm,pair,ts,b0,cgl); break;
    case 12: mid_body<4,2>(act,cg,Bm,partial,pm,pair,ts,b0,cgl); break;
    case 13: mid_body<4,3>(act,cg,Bm,partial,pm,pair,ts,b0,cgl); break;
    case 14: mid_body<4,4>(act,cg,Bm,partial,pm,pair,ts,b0,cgl); break;
    case 15: mid_body<5,0>(act,cg,Bm,partial,pm,pair,ts,b0,cgl); break;
    case 16: mid_body<5,1>(act,cg,Bm,partial,pm,pair,ts,b0,cgl); break;
    case 17: mid_body<5,2>(act,cg,Bm,partial,pm,pair,ts,b0,cgl); break;
    case 18: mid_body<5,3>(act,cg,Bm,partial,pm,pair,ts,b0,cgl); break;
    case 19: mid_body<5,4>(act,cg,Bm,partial,pm,pair,ts,b0,cgl); break;
    case 20: mid_body<5,5>(act,cg,Bm,partial,pm,pair,ts,b0,cgl); break;
    default: break;
  }
}

__global__ __launch_bounds__(256)
void k_scale(const float* __restrict__ partial, const float* __restrict__ mstd,
             float* __restrict__ scale, GMeta gm){
  int c=blockIdx.x*256+threadIdx.x;
  if (c>=MS_LEN) return;
  int l=0;
  #pragma unroll
  for (int i=1;i<6;++i) if (c>=gm.ms_off[i]) l=i;
  float ss=0.f;
  for (int g=0;g<NGRP;++g) ss += partial[(size_t)g*MS_LEN+c];
  float bstd = sqrtf(ss/(128.f*(float)(2*l+1)));
  scale[c] = 1.f/(0.5f*(mstd[c]+bstd)+EPSV);
}

__global__ __launch_bounds__(256)
void k_buildA(const float2* __restrict__ wts, const float* __restrict__ scale,
              bf16* __restrict__ Am, GMeta gm){
  int i=blockIdx.x*256+threadIdx.x;
  if (i>=W_CPLX) return;
  int l=0;
  #pragma unroll
  for (int j=1;j<6;++j) if (i>=gm.w_off[j]) l=j;
  int j=i-gm.w_off[l];
  int mt=gm.mt[l];
  int o=j/mt, c=j-o*mt;
  float2 w=wts[i];
  float s=scale[gm.ms_off[l]+c];
  size_t K=(size_t)gm.K[l];
  bf16* Al=Am+gm.aoff[l];
  Al[o*K+c]          =__float2bfloat16(w.x*s);
  Al[o*K+mt+c]       =__float2bfloat16(-w.y*s);
  Al[(24+o)*K+c]     =__float2bfloat16(w.y*s);
  Al[(24+o)*K+mt+c]  =__float2bfloat16(w.x*s);
}

// GEMM with K split over blockIdx.y into 4 chunks; per-chunk 48x16 tile -> part
__global__ __launch_bounds__(256)
void k_gemm2(const bf16* __restrict__ Am, const bf16* __restrict__ Bm,
             float* __restrict__ part, GMeta gm){
  int bid=blockIdx.x, z=blockIdx.y;
  int l=0;
  #pragma unroll
  for (int i=1;i<6;++i) if (bid>=gm.tb[i]) l=i;
  int ntile=bid-gm.tb[l];
  int K=gm.K[l];
  int tid=threadIdx.x, lane=tid&63, w=tid>>6;
  int r=lane&15, kg=lane>>4;
  int nit=K>>7;
  int nz=(nit+3)>>2;
  int it0=z*nz, it1=(nit<it0+nz)?nit:(it0+nz);
  f32x4 acc0={0.f,0.f,0.f,0.f}, acc1=acc0, acc2=acc0;
  __shared__ float red[3072];
  if (it0<it1){
    const bf16* Al=Am+gm.aoff[l];
    const bf16* Bl=Bm+gm.boff[l];
    size_t koff=(size_t)(w*32+kg*8)+(size_t)it0*128;
    const short8* pa0=(const short8*)(Al+(size_t)r*K+koff);
    const short8* pa1=(const short8*)(Al+(size_t)(16+r)*K+koff);
    const short8* pa2=(const short8*)(Al+(size_t)(32+r)*K+koff);
    const short8* pb =(const short8*)(Bl+(size_t)(ntile*16+r)*K+koff);
    short8 ca0=*pa0, ca1=*pa1, ca2=*pa2, cb=*pb;
    for (int it=it0+1; it<it1; ++it){
      pa0+=16; pa1+=16; pa2+=16; pb+=16;
      short8 na0=*pa0, na1=*pa1, na2=*pa2, nb_=*pb;
      acc0=__builtin_amdgcn_mfma_f32_16x16x32_bf16(ca0,cb,acc0,0,0,0);
      acc1=__builtin_amdgcn_mfma_f32_16x16x32_bf16(ca1,cb,acc1,0,0,0);
      acc2=__builtin_amdgcn_mfma_f32_16x16x32_bf16(ca2,cb,acc2,0,0,0);
      ca0=na0; ca1=na1; ca2=na2; cb=nb_;
    }
    acc0=__builtin_amdgcn_mfma_f32_16x16x32_bf16(ca0,cb,acc0,0,0,0);
    acc1=__builtin_amdgcn_mfma_f32_16x16x32_bf16(ca1,cb,acc1,0,0,0);
    acc2=__builtin_amdgcn_mfma_f32_16x16x32_bf16(ca2,cb,acc2,0,0,0);
  }
  #pragma unroll
  for (int reg=0;reg<4;++reg){
    int row0=kg*4+reg;
    red[(w*48+row0)*16+r]     =acc0[reg];
    red[(w*48+16+row0)*16+r]  =acc1[reg];
    red[(w*48+32+row0)*16+r]  =acc2[reg];
  }
  __syncthreads();
  float* po = part + (size_t)(bid*4+z)*768;
  for (int e=tid;e<768;e+=256)
    po[e]=red[e]+red[768+e]+red[1536+e]+red[2304+e];
}

__global__ __launch_bounds__(256)
void k_red(const float* __restrict__ part, float* __restrict__ outf,
           GMeta gm, int b0){
  int bid=blockIdx.x;
  int l=0;
  #pragma unroll
  for (int i=1;i<6;++i) if (bid>=gm.tb[i]) l=i;
  int ntile=bid-gm.tb[l];
  int nm=2*l+1;
  const float* po = part + (size_t)bid*4*768;
  for (int e=threadIdx.x;e<768;e+=256){
    float sv=po[e]+po[768+e]+po[1536+e]+po[2304+e];
    int o=e>>4, cc=e&15;
    int n=ntile*16+cc;
    int bb=n/nm, m=n-bb*nm;
    int b=b0+bb;
    int oo=(o<24)?o:(o-24);
    int comp=(o<24)?0:1;
    outf[((size_t)b*IN_LEN + 24*l*l + oo*nm + m)*2 + comp]=sv;
  }
}

extern "C" void kernel_launch(void* const* d_in, const int* in_sizes, int n_in,
                              void* d_out, int out_size, void* d_ws, size_t ws_size,
                              hipStream_t stream) {
  const float2* act  = (const float2*)d_in[0];
  const float2* wts  = (const float2*)d_in[1];
  const float*  mstd = (const float*)d_in[2];
  float* outf = (float*)d_out;
  (void)in_sizes; (void)n_in; (void)out_size;

  // ---- pass 1: counts ----
  int cnt[6]={0,0,0,0,0,0};
  for (int l1=0;l1<=5;++l1)
    for (int l2=0;l2<=l1;++l2)
      for (int l=l1-l2; l<=min(l1+l2,5); ++l) cnt[l]++;

  GMeta gm; PMeta pm; CMeta cm;
  gm.ms_off[0]=0;
  for (int l=0;l<6;++l){
    gm.mt[l]=576*cnt[l]; pm.mt[l]=gm.mt[l];
    gm.K[l]=2*gm.mt[l];  pm.K[l]=gm.K[l];
    gm.ms_off[l+1]=gm.ms_off[l]+gm.mt[l];
  }
  for (int l=0;l<6;++l) gm.w_off[l]=24*gm.ms_off[l];
  int atot=0;
  for (int l=0;l<6;++l){ gm.aoff[l]=atot; atot+=48*gm.K[l]; }

  // ---- pass 2: per-triple fill (except bb which needs boff) ----
  int cnt2[6]={0,0,0,0,0,0};
  int ncg=0, n=0;
  int tposArr[NTRI], lArr[NTRI], pidArr[NTRI];
  for (int l1=0;l1<=5;++l1)
    for (int l2=0;l2<=l1;++l2){
      int pid=l1*(l1+1)/2+l2;
      for (int l=l1-l2; l<=min(l1+l2,5); ++l){
        int tpos=cnt2[l]++;
        cm.l1[n]=(unsigned char)l1; cm.l2[n]=(unsigned char)l2; cm.lo[n]=(unsigned char)l;
        cm.cg_off[n]=ncg;
        if (l==l1-l2) pm.cgo0[pid]=ncg;
        pm.gch[pid][l]=gm.ms_off[l]+tpos*576;
        tposArr[n]=tpos; lArr[n]=l; pidArr[n]=pid;
        ncg += (2*l+1)*(2*l1+1);
        ++n;
      }
    }

  // ---- ws layout ----
  size_t ob=0;
  auto alloc=[&](size_t bytes){ size_t o=ob; ob=(ob+bytes+255)&~255ULL; return o; };
  size_t off_cg      = alloc((size_t)ncg*4);
  size_t off_scale   = alloc((size_t)MS_LEN*4);
  size_t off_partial = alloc((size_t)NGRP*MS_LEN*4);
  size_t off_A       = alloc((size_t)atot*2);
  size_t off_part    = alloc((size_t)288*4*768*4);   // worst case nb=128
  size_t off_B       = ob;

  size_t perB=0;
  for (int l=0;l<6;++l) perB += (size_t)(2*l+1)*gm.K[l]*2;
  int nb=16;
  for (int cand : {128,64,32,16})
    if (off_B + (size_t)cand*perB <= ws_size){ nb=cand; break; }

  { int bo=0; for (int l=0;l<6;++l){ gm.boff[l]=bo; bo+=nb*(2*l+1)*gm.K[l]; } }
  gm.tb[0]=0;
  for (int l=0;l<6;++l) gm.tb[l+1]=gm.tb[l]+nb*(2*l+1)/16;
  for (int i=0;i<NTRI;++i)
    pm.bb[pidArr[i]][lArr[i]] = gm.boff[lArr[i]] + tposArr[i]*576;

  uint8_t* wsb=(uint8_t*)d_ws;
  float* cg      =(float*)(wsb+off_cg);
  float* scale   =(float*)(wsb+off_scale);
  float* partial =(float*)(wsb+off_partial);
  bf16*  Am      =(bf16*)(wsb+off_A);
  float* part    =(float*)(wsb+off_part);
  bf16*  Bm      =(bf16*)(wsb+off_B);

  k_init_cg<<<NTRI,64,0,stream>>>(cg, cm);
  int tiles=gm.tb[6];
  if (nb==NB){
    k_mid2<<<dim3(63,NB/2),192,0,stream>>>(act,cg,Bm,partial,pm,0);
    k_scale<<<(MS_LEN+255)/256,256,0,stream>>>(partial,mstd,scale,gm);
    k_buildA<<<(W_CPLX+255)/256,256,0,stream>>>(wts,scale,Am,gm);
    k_gemm2<<<dim3(tiles,4),256,0,stream>>>(Am,Bm,part,gm);
    k_red<<<tiles,256,0,stream>>>(part,outf,gm,0);
  } else {
    for (int b0=0;b0<NB;b0+=nb)
      k_mid2<<<dim3(63,nb/2),192,0,stream>>>(act,cg,Bm,partial,pm,b0);
    k_scale<<<(MS_LEN+255)/256,256,0,stream>>>(partial,mstd,scale,gm);
    k_buildA<<<(W_CPLX+255)/256,256,0,stream>>>(wts,scale,Am,gm);
    for (int b0=0;b0<NB;b0+=nb){
      k_mid2<<<dim3(63,nb/2),192,0,stream>>>(act,cg,Bm,partial,pm,b0);
      k_gemm2<<<dim3(tiles,4),256,0,stream>>>(Am,Bm,part,gm);
      k_red<<<tiles,256,0,stream>>>(part,outf,gm,b0);
    }
  }
}

// Round 4
// 413.760 us; speedup vs baseline: 1.2765x; 1.2765x over previous
//
#include <hip/hip_runtime.h>
#include <hip/hip_bf16.h>
#include <math.h>

#define NTRI 69
#define NPAIR 21
#define NB 128
#define NGRP 64            // batch groups of 2 for sumsq partials
#define IN_LEN 864
#define MS_LEN 39744
#define W_CPLX 953856      // 24*MS_LEN
#define EPSV 1e-5f

typedef short short8 __attribute__((ext_vector_type(8)));
typedef float f32x4 __attribute__((ext_vector_type(4)));
typedef __hip_bfloat16 bf16;

struct CMeta { unsigned char l1[NTRI], l2[NTRI], lo[NTRI]; int cg_off[NTRI]; };
struct PMeta {
  int bb[NPAIR][6];     // B element base for (pair,l): boff[l]+tpos*576
  int gch[NPAIR][6];    // global channel base: ms_off[l]+tpos*576
  int cgo0[NPAIR];      // cg float offset of first triple of pair
  int K[6], mt[6];
};
struct GMeta { int aoff[6], boff[6], K[6], mt[6], w_off[6], ms_off[7], tb[7]; };

__constant__ double c_fac[18] = {
  1.0,1.0,2.0,6.0,24.0,120.0,720.0,5040.0,40320.0,362880.0,3628800.0,
  39916800.0,479001600.0,6227020800.0,87178291200.0,1307674368000.0,
  20922789888000.0,355687428096000.0 };

__device__ double cg_coef(int j1,int m1,int j2,int m2,int j,int m){
  if (m1+m2!=m) return 0.0;
  double pref = sqrt((2.0*j+1.0)*c_fac[j+j1-j2]*c_fac[j-j1+j2]*c_fac[j1+j2-j]/c_fac[j1+j2+j+1]);
  pref *= sqrt(c_fac[j+m]*c_fac[j-m]*c_fac[j1-m1]*c_fac[j1+m1]*c_fac[j2-m2]*c_fac[j2+m2]);
  int kmin = max(0, max(-(j-j2+m1), -(j-j1-m2)));
  int kmax = min(j1+j2-j, min(j1-m1, j2+m2));
  double s = 0.0;
  for (int k=kmin;k<=kmax;++k){
    double d = c_fac[k]*c_fac[j1+j2-j-k]*c_fac[j1-m1-k]*c_fac[j2+m2-k]*c_fac[j-j2+m1+k]*c_fac[j-j1-m2+k];
    s += ((k&1)? -1.0:1.0)/d;
  }
  return pref*s;
}

__global__ void k_init_cg(float* __restrict__ cg, CMeta cm){
  int tri = blockIdx.x;
  int l1=cm.l1[tri], l2=cm.l2[tri], l=cm.lo[tri];
  int n1=2*l1+1, nm=2*l+1;
  int n=nm*n1;
  for (int e=threadIdx.x; e<n; e+=blockDim.x){
    int mi=e/n1, xi=e-mi*n1;
    int m=mi-l, m1=xi-l1, m2=m-m1;
    float v=0.f;
    if (m2>=-l2 && m2<=l2) v=(float)cg_coef(l1,m1,l2,m2,l,m);
    cg[cm.cg_off[tri]+e]=v;
  }
}

// ---- pair-specialized middle computation (y streamed, f1+acc in regs) ----
template<int L1,int L2>
__device__ __forceinline__ void mid_body(
    const float2* __restrict__ act, const float* __restrict__ cg,
    bf16* __restrict__ Bm, float* __restrict__ partial,
    const PMeta& pm, int ts, int b0, float* cgl)
{
  constexpr int PID=L1*(L1+1)/2+L2;
  constexpr int N1=2*L1+1, N2=2*L2+1;
  constexpr int LMIN=L1-L2;
  constexpr int LMAX=(L1+L2<5)?(L1+L2):5;
  constexpr int NL=LMAX-LMIN+1;
  constexpr int ACCN=(LMAX+1)*(LMAX+1)-LMIN*LMIN;
  constexpr int CGTOT=ACCN*N1;
  for (int i=threadIdx.x;i<CGTOT;i+=192) cgl[i]=cg[pm.cgo0[PID]+i];
  __syncthreads();
  int t=ts/24, s=ts-24*t;
  int a1=24*L1*L1+t*N1;
  int a2=24*L2*L2+s*N2;
  int b=b0+(int)blockIdx.y*2;
  float ssum[NL];
  #pragma unroll
  for (int i=0;i<NL;++i) ssum[i]=0.f;
  #pragma unroll 1
  for (int bi=0;bi<2;++bi,++b){
    const float2* ab=act+(size_t)b*IN_LEN;
    float f1r[N1],f1i[N1];
    #pragma unroll
    for (int x=0;x<N1;++x){ float2 v=ab[a1+x]; f1r[x]=v.x; f1i[x]=v.y; }
    float accr[ACCN], acci[ACCN];
    #pragma unroll
    for (int i=0;i<ACCN;++i){ accr[i]=0.f; acci[i]=0.f; }
    #pragma unroll
    for (int y=0;y<N2;++y){
      float2 v2=ab[a2+y];
      float f2r=v2.x, f2i=v2.y;
      #pragma unroll
      for (int x=0;x<N1;++x){
        float pr=f1r[x]*f2r-f1i[x]*f2i;
        float pi=f1r[x]*f2i+f1i[x]*f2r;
        const int ma=(x-L1)+(y-L2);
        #pragma unroll
        for (int l=LMIN;l<=LMAX;++l){
          if (ma>=-l && ma<=l){
            const int idx=l*l-LMIN*LMIN+(ma+l);
            float cv=cgl[idx*N1+x];
            accr[idx]+=cv*pr;
            acci[idx]+=cv*pi;
          }
        }
      }
    }
    int brel=b-b0;
    #pragma unroll
    for (int l=LMIN;l<=LMAX;++l){
      const int nm=2*l+1, base=l*l-LMIN*LMIN;
      int Kl=pm.K[l], mtl=pm.mt[l];
      size_t rowb=(size_t)pm.bb[PID][l]+(size_t)brel*nm*Kl+ts;
      float ssl=0.f;
      #pragma unroll
      for (int mi=0;mi<nm;++mi){
        float fr=accr[base+mi], fi=acci[base+mi];
        ssl+=fr*fr+fi*fi;
        Bm[rowb+(size_t)mi*Kl]=__float2bfloat16(fr);
        Bm[rowb+(size_t)mi*Kl+mtl]=__float2bfloat16(fi);
      }
      ssum[l-LMIN]+=ssl;
    }
  }
  int pg=(b0>>1)+blockIdx.y;
  #pragma unroll
  for (int l=LMIN;l<=LMAX;++l)
    partial[(size_t)pg*MS_LEN+pm.gch[PID][l]+ts]=ssum[l-LMIN];
}

// Class A: ACCN <= 15  (pairs 00,10,11,20,21,30,40,50)
__global__ __launch_bounds__(192)
void k_midA(const float2* __restrict__ act, const float* __restrict__ cg,
            bf16* __restrict__ Bm, float* __restrict__ partial, PMeta pm, int b0){
  __shared__ float cgl[400];
  int idx = blockIdx.x/3, seg = blockIdx.x - idx*3;
  int ts = seg*192 + threadIdx.x;
  switch(idx){
    case 0: mid_body<0,0>(act,cg,Bm,partial,pm,ts,b0,cgl); break;
    case 1: mid_body<1,0>(act,cg,Bm,partial,pm,ts,b0,cgl); break;
    case 2: mid_body<1,1>(act,cg,Bm,partial,pm,ts,b0,cgl); break;
    case 3: mid_body<2,0>(act,cg,Bm,partial,pm,ts,b0,cgl); break;
    case 4: mid_body<2,1>(act,cg,Bm,partial,pm,ts,b0,cgl); break;
    case 5: mid_body<3,0>(act,cg,Bm,partial,pm,ts,b0,cgl); break;
    case 6: mid_body<4,0>(act,cg,Bm,partial,pm,ts,b0,cgl); break;
    case 7: mid_body<5,0>(act,cg,Bm,partial,pm,ts,b0,cgl); break;
    default: break;
  }
}

// Class B: ACCN 20..27  (pairs 22,31,41,51,52)
__global__ __launch_bounds__(192)
void k_midB(const float2* __restrict__ act, const float* __restrict__ cg,
            bf16* __restrict__ Bm, float* __restrict__ partial, PMeta pm, int b0){
  __shared__ float cgl[400];
  int idx = blockIdx.x/3, seg = blockIdx.x - idx*3;
  int ts = seg*192 + threadIdx.x;
  switch(idx){
    case 0: mid_body<2,2>(act,cg,Bm,partial,pm,ts,b0,cgl); break;
    case 1: mid_body<3,1>(act,cg,Bm,partial,pm,ts,b0,cgl); break;
    case 2: mid_body<4,1>(act,cg,Bm,partial,pm,ts,b0,cgl); break;
    case 3: mid_body<5,1>(act,cg,Bm,partial,pm,ts,b0,cgl); break;
    case 4: mid_body<5,2>(act,cg,Bm,partial,pm,ts,b0,cgl); break;
    default: break;
  }
}

// Class C: ACCN 32..36  (pairs 32,33,42,43,44,53,54,55)
__global__ __launch_bounds__(192)
void k_midC(const float2* __restrict__ act, const float* __restrict__ cg,
            bf16* __restrict__ Bm, float* __restrict__ partial, PMeta pm, int b0){
  __shared__ float cgl[400];
  int idx = blockIdx.x/3, seg = blockIdx.x - idx*3;
  int ts = seg*192 + threadIdx.x;
  switch(idx){
    case 0: mid_body<3,2>(act,cg,Bm,partial,pm,ts,b0,cgl); break;
    case 1: mid_body<3,3>(act,cg,Bm,partial,pm,ts,b0,cgl); break;
    case 2: mid_body<4,2>(act,cg,Bm,partial,pm,ts,b0,cgl); break;
    case 3: mid_body<4,3>(act,cg,Bm,partial,pm,ts,b0,cgl); break;
    case 4: mid_body<4,4>(act,cg,Bm,partial,pm,ts,b0,cgl); break;
    case 5: mid_body<5,3>(act,cg,Bm,partial,pm,ts,b0,cgl); break;
    case 6: mid_body<5,4>(act,cg,Bm,partial,pm,ts,b0,cgl); break;
    case 7: mid_body<5,5>(act,cg,Bm,partial,pm,ts,b0,cgl); break;
    default: break;
  }
}

__global__ __launch_bounds__(256)
void k_scale(const float* __restrict__ partial, const float* __restrict__ mstd,
             float* __restrict__ scale, GMeta gm){
  int c=blockIdx.x*256+threadIdx.x;
  if (c>=MS_LEN) return;
  int l=0;
  #pragma unroll
  for (int i=1;i<6;++i) if (c>=gm.ms_off[i]) l=i;
  float ss=0.f;
  for (int g=0;g<NGRP;++g) ss += partial[(size_t)g*MS_LEN+c];
  float bstd = sqrtf(ss/(128.f*(float)(2*l+1)));
  scale[c] = 1.f/(0.5f*(mstd[c]+bstd)+EPSV);
}

__global__ __launch_bounds__(256)
void k_buildA(const float2* __restrict__ wts, const float* __restrict__ scale,
              bf16* __restrict__ Am, GMeta gm){
  int i=blockIdx.x*256+threadIdx.x;
  if (i>=W_CPLX) return;
  int l=0;
  #pragma unroll
  for (int j=1;j<6;++j) if (i>=gm.w_off[j]) l=j;
  int j=i-gm.w_off[l];
  int mt=gm.mt[l];
  int o=j/mt, c=j-o*mt;
  float2 w=wts[i];
  float s=scale[gm.ms_off[l]+c];
  size_t K=(size_t)gm.K[l];
  bf16* Al=Am+gm.aoff[l];
  Al[o*K+c]          =__float2bfloat16(w.x*s);
  Al[o*K+mt+c]       =__float2bfloat16(-w.y*s);
  Al[(24+o)*K+c]     =__float2bfloat16(w.y*s);
  Al[(24+o)*K+mt+c]  =__float2bfloat16(w.x*s);
}

// GEMM with K split over blockIdx.y into 4 chunks; per-chunk 48x16 tile -> part
__global__ __launch_bounds__(256)
void k_gemm2(const bf16* __restrict__ Am, const bf16* __restrict__ Bm,
             float* __restrict__ part, GMeta gm){
  int bid=blockIdx.x, z=blockIdx.y;
  int l=0;
  #pragma unroll
  for (int i=1;i<6;++i) if (bid>=gm.tb[i]) l=i;
  int ntile=bid-gm.tb[l];
  int K=gm.K[l];
  int tid=threadIdx.x, lane=tid&63, w=tid>>6;
  int r=lane&15, kg=lane>>4;
  int nit=K>>7;
  int nz=(nit+3)>>2;
  int it0=z*nz, it1=(nit<it0+nz)?nit:(it0+nz);
  f32x4 acc0={0.f,0.f,0.f,0.f}, acc1=acc0, acc2=acc0;
  __shared__ float red[3072];
  if (it0<it1){
    const bf16* Al=Am+gm.aoff[l];
    const bf16* Bl=Bm+gm.boff[l];
    size_t koff=(size_t)(w*32+kg*8)+(size_t)it0*128;
    const short8* pa0=(const short8*)(Al+(size_t)r*K+koff);
    const short8* pa1=(const short8*)(Al+(size_t)(16+r)*K+koff);
    const short8* pa2=(const short8*)(Al+(size_t)(32+r)*K+koff);
    const short8* pb =(const short8*)(Bl+(size_t)(ntile*16+r)*K+koff);
    short8 ca0=*pa0, ca1=*pa1, ca2=*pa2, cb=*pb;
    for (int it=it0+1; it<it1; ++it){
      pa0+=16; pa1+=16; pa2+=16; pb+=16;
      short8 na0=*pa0, na1=*pa1, na2=*pa2, nb_=*pb;
      acc0=__builtin_amdgcn_mfma_f32_16x16x32_bf16(ca0,cb,acc0,0,0,0);
      acc1=__builtin_amdgcn_mfma_f32_16x16x32_bf16(ca1,cb,acc1,0,0,0);
      acc2=__builtin_amdgcn_mfma_f32_16x16x32_bf16(ca2,cb,acc2,0,0,0);
      ca0=na0; ca1=na1; ca2=na2; cb=nb_;
    }
    acc0=__builtin_amdgcn_mfma_f32_16x16x32_bf16(ca0,cb,acc0,0,0,0);
    acc1=__builtin_amdgcn_mfma_f32_16x16x32_bf16(ca1,cb,acc1,0,0,0);
    acc2=__builtin_amdgcn_mfma_f32_16x16x32_bf16(ca2,cb,acc2,0,0,0);
  }
  #pragma unroll
  for (int reg=0;reg<4;++reg){
    int row0=kg*4+reg;
    red[(w*48+row0)*16+r]     =acc0[reg];
    red[(w*48+16+row0)*16+r]  =acc1[reg];
    red[(w*48+32+row0)*16+r]  =acc2[reg];
  }
  __syncthreads();
  float* po = part + (size_t)(bid*4+z)*768;
  for (int e=tid;e<768;e+=256)
    po[e]=red[e]+red[768+e]+red[1536+e]+red[2304+e];
}

__global__ __launch_bounds__(256)
void k_red(const float* __restrict__ part, float* __restrict__ outf,
           GMeta gm, int b0){
  int bid=blockIdx.x;
  int l=0;
  #pragma unroll
  for (int i=1;i<6;++i) if (bid>=gm.tb[i]) l=i;
  int ntile=bid-gm.tb[l];
  int nm=2*l+1;
  const float* po = part + (size_t)bid*4*768;
  for (int e=threadIdx.x;e<768;e+=256){
    float sv=po[e]+po[768+e]+po[1536+e]+po[2304+e];
    int o=e>>4, cc=e&15;
    int n=ntile*16+cc;
    int bb=n/nm, m=n-bb*nm;
    int b=b0+bb;
    int oo=(o<24)?o:(o-24);
    int comp=(o<24)?0:1;
    outf[((size_t)b*IN_LEN + 24*l*l + oo*nm + m)*2 + comp]=sv;
  }
}

static void launch_mids(const float2* act, const float* cg, bf16* Bm,
                        float* partial, const PMeta& pm, int b0, int nb,
                        hipStream_t stream){
  dim3 gA(8*3, nb/2), gB(5*3, nb/2), gC(8*3, nb/2);
  k_midA<<<gA,192,0,stream>>>(act,cg,Bm,partial,pm,b0);
  k_midB<<<gB,192,0,stream>>>(act,cg,Bm,partial,pm,b0);
  k_midC<<<gC,192,0,stream>>>(act,cg,Bm,partial,pm,b0);
}

extern "C" void kernel_launch(void* const* d_in, const int* in_sizes, int n_in,
                              void* d_out, int out_size, void* d_ws, size_t ws_size,
                              hipStream_t stream) {
  const float2* act  = (const float2*)d_in[0];
  const float2* wts  = (const float2*)d_in[1];
  const float*  mstd = (const float*)d_in[2];
  float* outf = (float*)d_out;
  (void)in_sizes; (void)n_in; (void)out_size;

  // ---- pass 1: counts ----
  int cnt[6]={0,0,0,0,0,0};
  for (int l1=0;l1<=5;++l1)
    for (int l2=0;l2<=l1;++l2)
      for (int l=l1-l2; l<=min(l1+l2,5); ++l) cnt[l]++;

  GMeta gm; PMeta pm; CMeta cm;
  gm.ms_off[0]=0;
  for (int l=0;l<6;++l){
    gm.mt[l]=576*cnt[l]; pm.mt[l]=gm.mt[l];
    gm.K[l]=2*gm.mt[l];  pm.K[l]=gm.K[l];
    gm.ms_off[l+1]=gm.ms_off[l]+gm.mt[l];
  }
  for (int l=0;l<6;++l) gm.w_off[l]=24*gm.ms_off[l];
  int atot=0;
  for (int l=0;l<6;++l){ gm.aoff[l]=atot; atot+=48*gm.K[l]; }

  // ---- pass 2: per-triple fill ----
  int cnt2[6]={0,0,0,0,0,0};
  int ncg=0, n=0;
  int tposArr[NTRI], lArr[NTRI], pidArr[NTRI];
  for (int l1=0;l1<=5;++l1)
    for (int l2=0;l2<=l1;++l2){
      int pid=l1*(l1+1)/2+l2;
      for (int l=l1-l2; l<=min(l1+l2,5); ++l){
        int tpos=cnt2[l]++;
        cm.l1[n]=(unsigned char)l1; cm.l2[n]=(unsigned char)l2; cm.lo[n]=(unsigned char)l;
        cm.cg_off[n]=ncg;
        if (l==l1-l2) pm.cgo0[pid]=ncg;
        pm.gch[pid][l]=gm.ms_off[l]+tpos*576;
        tposArr[n]=tpos; lArr[n]=l; pidArr[n]=pid;
        ncg += (2*l+1)*(2*l1+1);
        ++n;
      }
    }

  // ---- ws layout ----
  size_t ob=0;
  auto alloc=[&](size_t bytes){ size_t o=ob; ob=(ob+bytes+255)&~255ULL; return o; };
  size_t off_cg      = alloc((size_t)ncg*4);
  size_t off_scale   = alloc((size_t)MS_LEN*4);
  size_t off_partial = alloc((size_t)NGRP*MS_LEN*4);
  size_t off_A       = alloc((size_t)atot*2);
  size_t off_part    = alloc((size_t)288*4*768*4);   // worst case nb=128
  size_t off_B       = ob;

  size_t perB=0;
  for (int l=0;l<6;++l) perB += (size_t)(2*l+1)*gm.K[l]*2;
  int nb=16;
  for (int cand : {128,64,32,16})
    if (off_B + (size_t)cand*perB <= ws_size){ nb=cand; break; }

  { int bo=0; for (int l=0;l<6;++l){ gm.boff[l]=bo; bo+=nb*(2*l+1)*gm.K[l]; } }
  gm.tb[0]=0;
  for (int l=0;l<6;++l) gm.tb[l+1]=gm.tb[l]+nb*(2*l+1)/16;
  for (int i=0;i<NTRI;++i)
    pm.bb[pidArr[i]][lArr[i]] = gm.boff[lArr[i]] + tposArr[i]*576;

  uint8_t* wsb=(uint8_t*)d_ws;
  float* cg      =(float*)(wsb+off_cg);
  float* scale   =(float*)(wsb+off_scale);
  float* partial =(float*)(wsb+off_partial);
  bf16*  Am      =(bf16*)(wsb+off_A);
  float* part    =(float*)(wsb+off_part);
  bf16*  Bm      =(bf16*)(wsb+off_B);

  k_init_cg<<<NTRI,64,0,stream>>>(cg, cm);
  int tiles=gm.tb[6];
  if (nb==NB){
    launch_mids(act,cg,Bm,partial,pm,0,NB,stream);
    k_scale<<<(MS_LEN+255)/256,256,0,stream>>>(partial,mstd,scale,gm);
    k_buildA<<<(W_CPLX+255)/256,256,0,stream>>>(wts,scale,Am,gm);
    k_gemm2<<<dim3(tiles,4),256,0,stream>>>(Am,Bm,part,gm);
    k_red<<<tiles,256,0,stream>>>(part,outf,gm,0);
  } else {
    for (int b0=0;b0<NB;b0+=nb)
      launch_mids(act,cg,Bm,partial,pm,b0,nb,stream);
    k_scale<<<(MS_LEN+255)/256,256,0,stream>>>(partial,mstd,scale,gm);
    k_buildA<<<(W_CPLX+255)/256,256,0,stream>>>(wts,scale,Am,gm);
    for (int b0=0;b0<NB;b0+=nb){
      launch_mids(act,cg,Bm,partial,pm,b0,nb,stream);
      k_gemm2<<<dim3(tiles,4),256,0,stream>>>(Am,Bm,part,gm);
      k_red<<<tiles,256,0,stream>>>(part,outf,gm,b0);
    }
  }
}

// Round 5
// 259.875 us; speedup vs baseline: 2.0323x; 1.5922x over previous
//
#include <hip/hip_runtime.h>
#include <hip/hip_bf16.h>
#include <math.h>

#define NTRI 69
#define NB 128
#define NGRP 64            // batch groups of 2 for sumsq partials
#define IN_LEN 864
#define MS_LEN 39744
#define W_CPLX 953856      // 24*MS_LEN
#define EPSV 1e-5f

typedef short short8 __attribute__((ext_vector_type(8)));
typedef float f32x4 __attribute__((ext_vector_type(4)));
typedef __hip_bfloat16 bf16;

// ---- compile-time triple tables ----
struct Tables { int l1[NTRI], l2[NTRI], lo[NTRI], tpos[NTRI], cgoff[NTRI], ncg; };
constexpr Tables make_tables(){
  Tables t{};
  int cnt[6]={0,0,0,0,0,0}; int n=0, ncg=0;
  for(int a=0;a<=5;++a)
    for(int b=0;b<=a;++b)
      for(int l=a-b; l<=((a+b<5)?(a+b):5); ++l){
        t.l1[n]=a; t.l2[n]=b; t.lo[n]=l; t.tpos[n]=cnt[l]++;
        t.cgoff[n]=ncg; ncg+=(2*l+1)*(2*a+1); ++n;
      }
  t.ncg=ncg; return t;
}
constexpr Tables TB = make_tables();
constexpr int MT[6]   = {3456,5760,7488,8064,8064,6912};
constexpr int MSOFF[7]= {0,3456,9216,16704,24768,32832,39744};

struct MPar { int bb[NTRI]; int gch[NTRI]; };   // runtime B bases (nb-dependent)
struct CMeta { unsigned char l1[NTRI], l2[NTRI], lo[NTRI]; int cg_off[NTRI]; };
struct GMeta { int aoff[6], boff[6], K[6], mt[6], w_off[6], ms_off[7], tb[7]; };

__constant__ double c_fac[18] = {
  1.0,1.0,2.0,6.0,24.0,120.0,720.0,5040.0,40320.0,362880.0,3628800.0,
  39916800.0,479001600.0,6227020800.0,87178291200.0,1307674368000.0,
  20922789888000.0,355687428096000.0 };

__device__ double cg_coef(int j1,int m1,int j2,int m2,int j,int m){
  if (m1+m2!=m) return 0.0;
  double pref = sqrt((2.0*j+1.0)*c_fac[j+j1-j2]*c_fac[j-j1+j2]*c_fac[j1+j2-j]/c_fac[j1+j2+j+1]);
  pref *= sqrt(c_fac[j+m]*c_fac[j-m]*c_fac[j1-m1]*c_fac[j1+m1]*c_fac[j2-m2]*c_fac[j2+m2]);
  int kmin = max(0, max(-(j-j2+m1), -(j-j1-m2)));
  int kmax = min(j1+j2-j, min(j1-m1, j2+m2));
  double s = 0.0;
  for (int k=kmin;k<=kmax;++k){
    double d = c_fac[k]*c_fac[j1+j2-j-k]*c_fac[j1-m1-k]*c_fac[j2+m2-k]*c_fac[j-j2+m1+k]*c_fac[j-j1-m2+k];
    s += ((k&1)? -1.0:1.0)/d;
  }
  return pref*s;
}

__global__ void k_init_cg(float* __restrict__ cg, CMeta cm){
  int tri = blockIdx.x;
  int l1=cm.l1[tri], l2=cm.l2[tri], l=cm.lo[tri];
  int n1=2*l1+1, nm=2*l+1;
  int n=nm*n1;
  for (int e=threadIdx.x; e<n; e+=blockDim.x){
    int mi=e/n1, xi=e-mi*n1;
    int m=mi-l, m1=xi-l1, m2=m-m1;
    float v=0.f;
    if (m2>=-l2 && m2<=l2) v=(float)cg_coef(l1,m1,l2,m2,l,m);
    cg[cm.cg_off[tri]+e]=v;
  }
}

// ---- per-TRIPLE specialized middle kernel: one thread = (channel, 2 batches),
//      m-sequential accumulation -> only 2 live accumulators, ~60-90 VGPR ----
template<int TRI>
__device__ __forceinline__ void mid_body(
    const float2* __restrict__ act, const float* __restrict__ cg,
    bf16* __restrict__ Bm, float* __restrict__ partial,
    const MPar& mp, int ts, int b0, float* cgl)
{
  constexpr int L1=TB.l1[TRI], L2=TB.l2[TRI], L=TB.lo[TRI];
  constexpr int N1=2*L1+1, N2=2*L2+1, NM=2*L+1;
  constexpr int D=L1+L2-L;
  constexpr int MTL=MT[L], KL=2*MT[L];
  for (int i=threadIdx.x; i<NM*N1; i+=192) cgl[i]=cg[TB.cgoff[TRI]+i];
  __syncthreads();
  int t=ts/24, s=ts-24*t;
  const int a1=24*L1*L1+t*N1, a2=24*L2*L2+s*N2;
  float ss=0.f;
  const int bb=mp.bb[TRI];
  #pragma unroll 1
  for (int bi=0;bi<2;++bi){
    int brel=(int)blockIdx.y*2+bi;
    int b=b0+brel;
    const float2* ab=act+(size_t)b*IN_LEN;
    float f1r[N1],f1i[N1],f2r[N2],f2i[N2];
    #pragma unroll
    for (int x=0;x<N1;++x){ float2 v=ab[a1+x]; f1r[x]=v.x; f1i[x]=v.y; }
    #pragma unroll
    for (int y=0;y<N2;++y){ float2 v=ab[a2+y]; f2r[y]=v.x; f2i[y]=v.y; }
    size_t rowb=(size_t)bb+(size_t)brel*NM*KL+ts;
    #pragma unroll
    for (int m=0;m<NM;++m){
      float fr=0.f, fi=0.f;
      #pragma unroll
      for (int x=0;x<N1;++x){
        constexpr int dummy=0; (void)dummy;
        const int y=m-x+D;
        if (y>=0 && y<N2){
          float cv=cgl[m*N1+x];
          float pr=f1r[x]*f2r[y]-f1i[x]*f2i[y];
          float pi=f1r[x]*f2i[y]+f1i[x]*f2r[y];
          fr += cv*pr; fi += cv*pi;
        }
      }
      ss += fr*fr+fi*fi;
      Bm[rowb+(size_t)m*KL]     = __float2bfloat16(fr);
      Bm[rowb+(size_t)m*KL+MTL] = __float2bfloat16(fi);
    }
  }
  partial[(size_t)((b0>>1)+blockIdx.y)*MS_LEN + mp.gch[TRI] + ts] = ss;
}

__global__ __launch_bounds__(192)
void k_mid3(const float2* __restrict__ act, const float* __restrict__ cg,
            bf16* __restrict__ Bm, float* __restrict__ partial, MPar mp, int b0){
  __shared__ float cgl[121];
  int tri = blockIdx.x/3, seg = blockIdx.x - tri*3;
  int ts = seg*192 + threadIdx.x;
  #define CASE(T) case T: mid_body<T>(act,cg,Bm,partial,mp,ts,b0,cgl); break;
  switch(tri){
    CASE(0) CASE(1) CASE(2) CASE(3) CASE(4) CASE(5) CASE(6) CASE(7) CASE(8)
    CASE(9) CASE(10) CASE(11) CASE(12) CASE(13) CASE(14) CASE(15) CASE(16)
    CASE(17) CASE(18) CASE(19) CASE(20) CASE(21) CASE(22) CASE(23) CASE(24)
    CASE(25) CASE(26) CASE(27) CASE(28) CASE(29) CASE(30) CASE(31) CASE(32)
    CASE(33) CASE(34) CASE(35) CASE(36) CASE(37) CASE(38) CASE(39) CASE(40)
    CASE(41) CASE(42) CASE(43) CASE(44) CASE(45) CASE(46) CASE(47) CASE(48)
    CASE(49) CASE(50) CASE(51) CASE(52) CASE(53) CASE(54) CASE(55) CASE(56)
    CASE(57) CASE(58) CASE(59) CASE(60) CASE(61) CASE(62) CASE(63) CASE(64)
    CASE(65) CASE(66) CASE(67) CASE(68)
    default: break;
  }
  #undef CASE
}

__global__ __launch_bounds__(256)
void k_scale(const float* __restrict__ partial, const float* __restrict__ mstd,
             float* __restrict__ scale, GMeta gm){
  int c=blockIdx.x*256+threadIdx.x;
  if (c>=MS_LEN) return;
  int l=0;
  #pragma unroll
  for (int i=1;i<6;++i) if (c>=gm.ms_off[i]) l=i;
  float ss=0.f;
  for (int g=0;g<NGRP;++g) ss += partial[(size_t)g*MS_LEN+c];
  float bstd = sqrtf(ss/(128.f*(float)(2*l+1)));
  scale[c] = 1.f/(0.5f*(mstd[c]+bstd)+EPSV);
}

__global__ __launch_bounds__(256)
void k_buildA(const float2* __restrict__ wts, const float* __restrict__ scale,
              bf16* __restrict__ Am, GMeta gm){
  int i=blockIdx.x*256+threadIdx.x;
  if (i>=W_CPLX) return;
  int l=0;
  #pragma unroll
  for (int j=1;j<6;++j) if (i>=gm.w_off[j]) l=j;
  int j=i-gm.w_off[l];
  int mt=gm.mt[l];
  int o=j/mt, c=j-o*mt;
  float2 w=wts[i];
  float s=scale[gm.ms_off[l]+c];
  size_t K=(size_t)gm.K[l];
  bf16* Al=Am+gm.aoff[l];
  Al[o*K+c]          =__float2bfloat16(w.x*s);
  Al[o*K+mt+c]       =__float2bfloat16(-w.y*s);
  Al[(24+o)*K+c]     =__float2bfloat16(w.y*s);
  Al[(24+o)*K+mt+c]  =__float2bfloat16(w.x*s);
}

// GEMM with K split over blockIdx.y into 4 chunks; per-chunk 48x16 tile -> part
__global__ __launch_bounds__(256)
void k_gemm2(const bf16* __restrict__ Am, const bf16* __restrict__ Bm,
             float* __restrict__ part, GMeta gm){
  int bid=blockIdx.x, z=blockIdx.y;
  int l=0;
  #pragma unroll
  for (int i=1;i<6;++i) if (bid>=gm.tb[i]) l=i;
  int ntile=bid-gm.tb[l];
  int K=gm.K[l];
  int tid=threadIdx.x, lane=tid&63, w=tid>>6;
  int r=lane&15, kg=lane>>4;
  int nit=K>>7;
  int nz=(nit+3)>>2;
  int it0=z*nz, it1=(nit<it0+nz)?nit:(it0+nz);
  f32x4 acc0={0.f,0.f,0.f,0.f}, acc1=acc0, acc2=acc0;
  __shared__ float red[3072];
  if (it0<it1){
    const bf16* Al=Am+gm.aoff[l];
    const bf16* Bl=Bm+gm.boff[l];
    size_t koff=(size_t)(w*32+kg*8)+(size_t)it0*128;
    const short8* pa0=(const short8*)(Al+(size_t)r*K+koff);
    const short8* pa1=(const short8*)(Al+(size_t)(16+r)*K+koff);
    const short8* pa2=(const short8*)(Al+(size_t)(32+r)*K+koff);
    const short8* pb =(const short8*)(Bl+(size_t)(ntile*16+r)*K+koff);
    short8 ca0=*pa0, ca1=*pa1, ca2=*pa2, cb=*pb;
    for (int it=it0+1; it<it1; ++it){
      pa0+=16; pa1+=16; pa2+=16; pb+=16;
      short8 na0=*pa0, na1=*pa1, na2=*pa2, nb_=*pb;
      acc0=__builtin_amdgcn_mfma_f32_16x16x32_bf16(ca0,cb,acc0,0,0,0);
      acc1=__builtin_amdgcn_mfma_f32_16x16x32_bf16(ca1,cb,acc1,0,0,0);
      acc2=__builtin_amdgcn_mfma_f32_16x16x32_bf16(ca2,cb,acc2,0,0,0);
      ca0=na0; ca1=na1; ca2=na2; cb=nb_;
    }
    acc0=__builtin_amdgcn_mfma_f32_16x16x32_bf16(ca0,cb,acc0,0,0,0);
    acc1=__builtin_amdgcn_mfma_f32_16x16x32_bf16(ca1,cb,acc1,0,0,0);
    acc2=__builtin_amdgcn_mfma_f32_16x16x32_bf16(ca2,cb,acc2,0,0,0);
  }
  #pragma unroll
  for (int reg=0;reg<4;++reg){
    int row0=kg*4+reg;
    red[(w*48+row0)*16+r]     =acc0[reg];
    red[(w*48+16+row0)*16+r]  =acc1[reg];
    red[(w*48+32+row0)*16+r]  =acc2[reg];
  }
  __syncthreads();
  float* po = part + (size_t)(bid*4+z)*768;
  for (int e=tid;e<768;e+=256)
    po[e]=red[e]+red[768+e]+red[1536+e]+red[2304+e];
}

__global__ __launch_bounds__(256)
void k_red(const float* __restrict__ part, float* __restrict__ outf,
           GMeta gm, int b0){
  int bid=blockIdx.x;
  int l=0;
  #pragma unroll
  for (int i=1;i<6;++i) if (bid>=gm.tb[i]) l=i;
  int ntile=bid-gm.tb[l];
  int nm=2*l+1;
  const float* po = part + (size_t)bid*4*768;
  for (int e=threadIdx.x;e<768;e+=256){
    float sv=po[e]+po[768+e]+po[1536+e]+po[2304+e];
    int o=e>>4, cc=e&15;
    int n=ntile*16+cc;
    int bb=n/nm, m=n-bb*nm;
    int b=b0+bb;
    int oo=(o<24)?o:(o-24);
    int comp=(o<24)?0:1;
    outf[((size_t)b*IN_LEN + 24*l*l + oo*nm + m)*2 + comp]=sv;
  }
}

extern "C" void kernel_launch(void* const* d_in, const int* in_sizes, int n_in,
                              void* d_out, int out_size, void* d_ws, size_t ws_size,
                              hipStream_t stream) {
  const float2* act  = (const float2*)d_in[0];
  const float2* wts  = (const float2*)d_in[1];
  const float*  mstd = (const float*)d_in[2];
  float* outf = (float*)d_out;
  (void)in_sizes; (void)n_in; (void)out_size;

  GMeta gm; CMeta cm; MPar mp;
  for (int l=0;l<6;++l){ gm.mt[l]=MT[l]; gm.K[l]=2*MT[l]; }
  for (int l=0;l<7;++l) gm.ms_off[l]=MSOFF[l];
  for (int l=0;l<6;++l) gm.w_off[l]=24*gm.ms_off[l];
  int atot=0;
  for (int l=0;l<6;++l){ gm.aoff[l]=atot; atot+=48*gm.K[l]; }
  for (int i=0;i<NTRI;++i){
    cm.l1[i]=(unsigned char)TB.l1[i]; cm.l2[i]=(unsigned char)TB.l2[i];
    cm.lo[i]=(unsigned char)TB.lo[i]; cm.cg_off[i]=TB.cgoff[i];
    mp.gch[i]=MSOFF[TB.lo[i]]+TB.tpos[i]*576;
  }
  int ncg=TB.ncg;

  // ---- ws layout ----
  size_t ob=0;
  auto alloc=[&](size_t bytes){ size_t o=ob; ob=(ob+bytes+255)&~255ULL; return o; };
  size_t off_cg      = alloc((size_t)ncg*4);
  size_t off_scale   = alloc((size_t)MS_LEN*4);
  size_t off_partial = alloc((size_t)NGRP*MS_LEN*4);
  size_t off_A       = alloc((size_t)atot*2);
  size_t off_part    = alloc((size_t)288*4*768*4);
  size_t off_B       = ob;

  size_t perB=0;
  for (int l=0;l<6;++l) perB += (size_t)(2*l+1)*gm.K[l]*2;
  int nb=16;
  for (int cand : {128,64,32,16})
    if (off_B + (size_t)cand*perB <= ws_size){ nb=cand; break; }

  { int bo=0; for (int l=0;l<6;++l){ gm.boff[l]=bo; bo+=nb*(2*l+1)*gm.K[l]; } }
  gm.tb[0]=0;
  for (int l=0;l<6;++l) gm.tb[l+1]=gm.tb[l]+nb*(2*l+1)/16;
  for (int i=0;i<NTRI;++i)
    mp.bb[i] = gm.boff[TB.lo[i]] + TB.tpos[i]*576;

  uint8_t* wsb=(uint8_t*)d_ws;
  float* cg      =(float*)(wsb+off_cg);
  float* scale   =(float*)(wsb+off_scale);
  float* partial =(float*)(wsb+off_partial);
  bf16*  Am      =(bf16*)(wsb+off_A);
  float* part    =(float*)(wsb+off_part);
  bf16*  Bm      =(bf16*)(wsb+off_B);

  k_init_cg<<<NTRI,64,0,stream>>>(cg, cm);
  int tiles=gm.tb[6];
  if (nb==NB){
    k_mid3<<<dim3(NTRI*3,NB/2),192,0,stream>>>(act,cg,Bm,partial,mp,0);
    k_scale<<<(MS_LEN+255)/256,256,0,stream>>>(partial,mstd,scale,gm);
    k_buildA<<<(W_CPLX+255)/256,256,0,stream>>>(wts,scale,Am,gm);
    k_gemm2<<<dim3(tiles,4),256,0,stream>>>(Am,Bm,part,gm);
    k_red<<<tiles,256,0,stream>>>(part,outf,gm,0);
  } else {
    for (int b0=0;b0<NB;b0+=nb)
      k_mid3<<<dim3(NTRI*3,nb/2),192,0,stream>>>(act,cg,Bm,partial,mp,b0);
    k_scale<<<(MS_LEN+255)/256,256,0,stream>>>(partial,mstd,scale,gm);
    k_buildA<<<(W_CPLX+255)/256,256,0,stream>>>(wts,scale,Am,gm);
    for (int b0=0;b0<NB;b0+=nb){
      k_mid3<<<dim3(NTRI*3,nb/2),192,0,stream>>>(act,cg,Bm,partial,mp,b0);
      k_gemm2<<<dim3(tiles,4),256,0,stream>>>(Am,Bm,part,gm);
      k_red<<<tiles,256,0,stream>>>(part,outf,gm,b0);
    }
  }
}

// Round 6
// 162.469 us; speedup vs baseline: 3.2508x; 1.5995x over previous
//
#include <hip/hip_runtime.h>
#include <hip/hip_bf16.h>
#include <math.h>

#define NTRI 69
#define NB 128
#define IN_LEN 864
#define MS_LEN 39744
#define W_CPLX 953856      // 24*MS_LEN
#define EPSV 1e-5f

typedef short short8 __attribute__((ext_vector_type(8)));
typedef float f32x4 __attribute__((ext_vector_type(4)));
typedef __hip_bfloat16 bf16;

// ---- compile-time triple tables ----
struct Tables { int l1[NTRI], l2[NTRI], lo[NTRI], tpos[NTRI], cgoff[NTRI], ncg; };
constexpr Tables make_tables(){
  Tables t{};
  int cnt[6]={0,0,0,0,0,0}; int n=0, ncg=0;
  for(int a=0;a<=5;++a)
    for(int b=0;b<=a;++b)
      for(int l=a-b; l<=((a+b<5)?(a+b):5); ++l){
        t.l1[n]=a; t.l2[n]=b; t.lo[n]=l; t.tpos[n]=cnt[l]++;
        t.cgoff[n]=ncg; ncg+=(2*l+1)*(2*a+1); ++n;
      }
  t.ncg=ncg; return t;
}
constexpr Tables TB = make_tables();
constexpr int MT[6]   = {3456,5760,7488,8064,8064,6912};
constexpr int MSOFF[7]= {0,3456,9216,16704,24768,32832,39744};

struct MPar {
  int bb[NTRI];                 // B column base (elements) of triple within its l: boff[l]+tpos*1152
  int gch[NTRI];                // global middle-channel base
  unsigned char otri[NTRI*3];   // heavy-first block order: tri
  unsigned char oseg[NTRI*3];   // heavy-first block order: segment
};
struct CMeta { unsigned char l1[NTRI], l2[NTRI], lo[NTRI]; int cg_off[NTRI]; };
struct GMeta { int aoff[6], boff[6], K[6], mt[6], w_off[6], ms_off[7], tb[7]; };

__constant__ double c_fac[18] = {
  1.0,1.0,2.0,6.0,24.0,120.0,720.0,5040.0,40320.0,362880.0,3628800.0,
  39916800.0,479001600.0,6227020800.0,87178291200.0,1307674368000.0,
  20922789888000.0,355687428096000.0 };

__device__ double cg_coef(int j1,int m1,int j2,int m2,int j,int m){
  if (m1+m2!=m) return 0.0;
  double pref = sqrt((2.0*j+1.0)*c_fac[j+j1-j2]*c_fac[j-j1+j2]*c_fac[j1+j2-j]/c_fac[j1+j2+j+1]);
  pref *= sqrt(c_fac[j+m]*c_fac[j-m]*c_fac[j1-m1]*c_fac[j1+m1]*c_fac[j2-m2]*c_fac[j2+m2]);
  int kmin = max(0, max(-(j-j2+m1), -(j-j1-m2)));
  int kmax = min(j1+j2-j, min(j1-m1, j2+m2));
  double s = 0.0;
  for (int k=kmin;k<=kmax;++k){
    double d = c_fac[k]*c_fac[j1+j2-j-k]*c_fac[j1-m1-k]*c_fac[j2+m2-k]*c_fac[j-j2+m1+k]*c_fac[j-j1-m2+k];
    s += ((k&1)? -1.0:1.0)/d;
  }
  return pref*s;
}

__global__ void k_init_cg(float* __restrict__ cg, CMeta cm){
  int tri = blockIdx.x;
  int l1=cm.l1[tri], l2=cm.l2[tri], l=cm.lo[tri];
  int n1=2*l1+1, nm=2*l+1;
  int n=nm*n1;
  for (int e=threadIdx.x; e<n; e+=blockDim.x){
    int mi=e/n1, xi=e-mi*n1;
    int m=mi-l, m1=xi-l1, m2=m-m1;
    float v=0.f;
    if (m2>=-l2 && m2<=l2) v=(float)cg_coef(l1,m1,l2,m2,l,m);
    cg[cm.cg_off[tri]+e]=v;
  }
}

// ---- per-TRIPLE specialized middle kernel: one thread = (channel, 1 batch) ----
template<int TRI>
__device__ __forceinline__ void mid_body(
    const float2* __restrict__ act, const float* __restrict__ cg,
    bf16* __restrict__ Bm, float* __restrict__ partial,
    const MPar& mp, int ts, int b0, float* cgl)
{
  constexpr int L1=TB.l1[TRI], L2=TB.l2[TRI], L=TB.lo[TRI];
  constexpr int N1=2*L1+1, N2=2*L2+1, NM=2*L+1;
  constexpr int D=L1+L2-L;
  constexpr int MTL=MT[L], KL=2*MTL;
  for (int i=threadIdx.x; i<NM*N1; i+=192) cgl[i]=cg[TB.cgoff[TRI]+i];
  __syncthreads();
  int t=ts/24, s=ts-24*t;
  const int a1=24*L1*L1+t*N1, a2=24*L2*L2+s*N2;
  const int brel=(int)blockIdx.y;
  const int b=b0+brel;
  const float2* ab=act+(size_t)b*IN_LEN;
  float f1r[N1],f1i[N1],f2r[N2],f2i[N2];
  #pragma unroll
  for (int x=0;x<N1;++x){ float2 v=ab[a1+x]; f1r[x]=v.x; f1i[x]=v.y; }
  #pragma unroll
  for (int y=0;y<N2;++y){ float2 v=ab[a2+y]; f2r[y]=v.x; f2i[y]=v.y; }
  float ss=0.f;
  size_t rowb=(size_t)mp.bb[TRI]+(size_t)brel*NM*KL+2*ts;
  #pragma unroll
  for (int m=0;m<NM;++m){
    float fr=0.f, fi=0.f;
    #pragma unroll
    for (int x=0;x<N1;++x){
      const int y=m-x+D;
      if (y>=0 && y<N2){
        float cv=cgl[m*N1+x];
        fr += cv*(f1r[x]*f2r[y]-f1i[x]*f2i[y]);
        fi += cv*(f1r[x]*f2i[y]+f1i[x]*f2r[y]);
      }
    }
    ss += fr*fr+fi*fi;
    union { bf16 h[2]; unsigned u; } pk;
    pk.h[0]=__float2bfloat16(fr); pk.h[1]=__float2bfloat16(fi);
    *reinterpret_cast<unsigned*>(Bm+rowb+(size_t)m*KL)=pk.u;
  }
  partial[(size_t)b*MS_LEN + mp.gch[TRI] + ts] = ss;
}

__global__ __launch_bounds__(192,4)
void k_mid3(const float2* __restrict__ act, const float* __restrict__ cg,
            bf16* __restrict__ Bm, float* __restrict__ partial, MPar mp, int b0){
  __shared__ float cgl[121];
  int tri = mp.otri[blockIdx.x], seg = mp.oseg[blockIdx.x];
  int ts = seg*192 + threadIdx.x;
  #define CASE(T) case T: mid_body<T>(act,cg,Bm,partial,mp,ts,b0,cgl); break;
  switch(tri){
    CASE(0) CASE(1) CASE(2) CASE(3) CASE(4) CASE(5) CASE(6) CASE(7) CASE(8)
    CASE(9) CASE(10) CASE(11) CASE(12) CASE(13) CASE(14) CASE(15) CASE(16)
    CASE(17) CASE(18) CASE(19) CASE(20) CASE(21) CASE(22) CASE(23) CASE(24)
    CASE(25) CASE(26) CASE(27) CASE(28) CASE(29) CASE(30) CASE(31) CASE(32)
    CASE(33) CASE(34) CASE(35) CASE(36) CASE(37) CASE(38) CASE(39) CASE(40)
    CASE(41) CASE(42) CASE(43) CASE(44) CASE(45) CASE(46) CASE(47) CASE(48)
    CASE(49) CASE(50) CASE(51) CASE(52) CASE(53) CASE(54) CASE(55) CASE(56)
    CASE(57) CASE(58) CASE(59) CASE(60) CASE(61) CASE(62) CASE(63) CASE(64)
    CASE(65) CASE(66) CASE(67) CASE(68)
    default: break;
  }
  #undef CASE
}

__global__ __launch_bounds__(256)
void k_scale(const float* __restrict__ partial, const float* __restrict__ mstd,
             float* __restrict__ scale, GMeta gm){
  int c=blockIdx.x*256+threadIdx.x;
  if (c>=MS_LEN) return;
  int l=0;
  #pragma unroll
  for (int i=1;i<6;++i) if (c>=gm.ms_off[i]) l=i;
  float ss=0.f;
  for (int g=0;g<NB;++g) ss += partial[(size_t)g*MS_LEN+c];
  float bstd = sqrtf(ss/(128.f*(float)(2*l+1)));
  scale[c] = 1.f/(0.5f*(mstd[c]+bstd)+EPSV);
}

// A with re/im-interleaved K to match B: col 2c = re-part, col 2c+1 = im-part
__global__ __launch_bounds__(256)
void k_buildA(const float2* __restrict__ wts, const float* __restrict__ scale,
              bf16* __restrict__ Am, GMeta gm){
  int i=blockIdx.x*256+threadIdx.x;
  if (i>=W_CPLX) return;
  int l=0;
  #pragma unroll
  for (int j=1;j<6;++j) if (i>=gm.w_off[j]) l=j;
  int j=i-gm.w_off[l];
  int mt=gm.mt[l];
  int o=j/mt, c=j-o*mt;
  float2 w=wts[i];
  float s=scale[gm.ms_off[l]+c];
  size_t K=(size_t)gm.K[l];
  bf16* Al=Am+gm.aoff[l];
  union { bf16 h[2]; unsigned u; } p0, p1;
  p0.h[0]=__float2bfloat16(w.x*s);  p0.h[1]=__float2bfloat16(-w.y*s);
  p1.h[0]=__float2bfloat16(w.y*s);  p1.h[1]=__float2bfloat16(w.x*s);
  *reinterpret_cast<unsigned*>(Al+(size_t)o*K+2*c)      = p0.u;
  *reinterpret_cast<unsigned*>(Al+(size_t)(24+o)*K+2*c) = p1.u;
}

// GEMM with K split over blockIdx.y into 4 chunks; per-chunk 48x16 tile -> part
__global__ __launch_bounds__(256)
void k_gemm2(const bf16* __restrict__ Am, const bf16* __restrict__ Bm,
             float* __restrict__ part, GMeta gm){
  int bid=blockIdx.x, z=blockIdx.y;
  int l=0;
  #pragma unroll
  for (int i=1;i<6;++i) if (bid>=gm.tb[i]) l=i;
  int ntile=bid-gm.tb[l];
  int K=gm.K[l];
  int tid=threadIdx.x, lane=tid&63, w=tid>>6;
  int r=lane&15, kg=lane>>4;
  int nit=K>>7;
  int nz=(nit+3)>>2;
  int it0=z*nz, it1=(nit<it0+nz)?nit:(it0+nz);
  f32x4 acc0={0.f,0.f,0.f,0.f}, acc1=acc0, acc2=acc0;
  __shared__ float red[3072];
  if (it0<it1){
    const bf16* Al=Am+gm.aoff[l];
    const bf16* Bl=Bm+gm.boff[l];
    size_t koff=(size_t)(w*32+kg*8)+(size_t)it0*128;
    const short8* pa0=(const short8*)(Al+(size_t)r*K+koff);
    const short8* pa1=(const short8*)(Al+(size_t)(16+r)*K+koff);
    const short8* pa2=(const short8*)(Al+(size_t)(32+r)*K+koff);
    const short8* pb =(const short8*)(Bl+(size_t)(ntile*16+r)*K+koff);
    short8 ca0=*pa0, ca1=*pa1, ca2=*pa2, cb=*pb;
    for (int it=it0+1; it<it1; ++it){
      pa0+=16; pa1+=16; pa2+=16; pb+=16;
      short8 na0=*pa0, na1=*pa1, na2=*pa2, nb_=*pb;
      acc0=__builtin_amdgcn_mfma_f32_16x16x32_bf16(ca0,cb,acc0,0,0,0);
      acc1=__builtin_amdgcn_mfma_f32_16x16x32_bf16(ca1,cb,acc1,0,0,0);
      acc2=__builtin_amdgcn_mfma_f32_16x16x32_bf16(ca2,cb,acc2,0,0,0);
      ca0=na0; ca1=na1; ca2=na2; cb=nb_;
    }
    acc0=__builtin_amdgcn_mfma_f32_16x16x32_bf16(ca0,cb,acc0,0,0,0);
    acc1=__builtin_amdgcn_mfma_f32_16x16x32_bf16(ca1,cb,acc1,0,0,0);
    acc2=__builtin_amdgcn_mfma_f32_16x16x32_bf16(ca2,cb,acc2,0,0,0);
  }
  #pragma unroll
  for (int reg=0;reg<4;++reg){
    int row0=kg*4+reg;
    red[(w*48+row0)*16+r]     =acc0[reg];
    red[(w*48+16+row0)*16+r]  =acc1[reg];
    red[(w*48+32+row0)*16+r]  =acc2[reg];
  }
  __syncthreads();
  float* po = part + (size_t)(bid*4+z)*768;
  for (int e=tid;e<768;e+=256)
    po[e]=red[e]+red[768+e]+red[1536+e]+red[2304+e];
}

__global__ __launch_bounds__(256)
void k_red(const float* __restrict__ part, float* __restrict__ outf,
           GMeta gm, int b0){
  int bid=blockIdx.x;
  int l=0;
  #pragma unroll
  for (int i=1;i<6;++i) if (bid>=gm.tb[i]) l=i;
  int ntile=bid-gm.tb[l];
  int nm=2*l+1;
  const float* po = part + (size_t)bid*4*768;
  for (int e=threadIdx.x;e<768;e+=256){
    float sv=po[e]+po[768+e]+po[1536+e]+po[2304+e];
    int o=e>>4, cc=e&15;
    int n=ntile*16+cc;
    int bb=n/nm, m=n-bb*nm;
    int b=b0+bb;
    int oo=(o<24)?o:(o-24);
    int comp=(o<24)?0:1;
    outf[((size_t)b*IN_LEN + 24*l*l + oo*nm + m)*2 + comp]=sv;
  }
}

extern "C" void kernel_launch(void* const* d_in, const int* in_sizes, int n_in,
                              void* d_out, int out_size, void* d_ws, size_t ws_size,
                              hipStream_t stream) {
  const float2* act  = (const float2*)d_in[0];
  const float2* wts  = (const float2*)d_in[1];
  const float*  mstd = (const float*)d_in[2];
  float* outf = (float*)d_out;
  (void)in_sizes; (void)n_in; (void)out_size;

  GMeta gm; CMeta cm; MPar mp;
  for (int l=0;l<6;++l){ gm.mt[l]=MT[l]; gm.K[l]=2*MT[l]; }
  for (int l=0;l<7;++l) gm.ms_off[l]=MSOFF[l];
  for (int l=0;l<6;++l) gm.w_off[l]=24*gm.ms_off[l];
  int atot=0;
  for (int l=0;l<6;++l){ gm.aoff[l]=atot; atot+=48*gm.K[l]; }
  for (int i=0;i<NTRI;++i){
    cm.l1[i]=(unsigned char)TB.l1[i]; cm.l2[i]=(unsigned char)TB.l2[i];
    cm.lo[i]=(unsigned char)TB.lo[i]; cm.cg_off[i]=TB.cgoff[i];
    mp.gch[i]=MSOFF[TB.lo[i]]+TB.tpos[i]*576;
  }
  int ncg=TB.ncg;

  // heavy-first block order: sort triples by per-thread slot count descending
  {
    int ordt[NTRI];
    for (int i=0;i<NTRI;++i) ordt[i]=i;
    for (int i=1;i<NTRI;++i){
      int v=ordt[i];
      int wv=(2*TB.lo[v]+1)*(2*TB.l1[v]+1);
      int j=i-1;
      while (j>=0){
        int wj=(2*TB.lo[ordt[j]]+1)*(2*TB.l1[ordt[j]]+1);
        if (wj>=wv) break;
        ordt[j+1]=ordt[j]; --j;
      }
      ordt[j+1]=v;
    }
    for (int i=0;i<NTRI;++i)
      for (int sgi=0;sgi<3;++sgi){
        mp.otri[i*3+sgi]=(unsigned char)ordt[i];
        mp.oseg[i*3+sgi]=(unsigned char)sgi;
      }
  }

  // ---- ws layout ----
  size_t ob=0;
  auto alloc=[&](size_t bytes){ size_t o=ob; ob=(ob+bytes+255)&~255ULL; return o; };
  size_t off_cg      = alloc((size_t)ncg*4);
  size_t off_scale   = alloc((size_t)MS_LEN*4);
  size_t off_partial = alloc((size_t)NB*MS_LEN*4);
  size_t off_A       = alloc((size_t)atot*2);
  size_t off_part    = alloc((size_t)288*4*768*4);
  size_t off_B       = ob;

  size_t perB=0;
  for (int l=0;l<6;++l) perB += (size_t)(2*l+1)*gm.K[l]*2;
  int nb=16;
  for (int cand : {128,64,32,16})
    if (off_B + (size_t)cand*perB <= ws_size){ nb=cand; break; }

  { int bo=0; for (int l=0;l<6;++l){ gm.boff[l]=bo; bo+=nb*(2*l+1)*gm.K[l]; } }
  gm.tb[0]=0;
  for (int l=0;l<6;++l) gm.tb[l+1]=gm.tb[l]+nb*(2*l+1)/16;
  for (int i=0;i<NTRI;++i)
    mp.bb[i] = gm.boff[TB.lo[i]] + TB.tpos[i]*1152;   // column base, interleaved K

  uint8_t* wsb=(uint8_t*)d_ws;
  float* cg      =(float*)(wsb+off_cg);
  float* scale   =(float*)(wsb+off_scale);
  float* partial =(float*)(wsb+off_partial);
  bf16*  Am      =(bf16*)(wsb+off_A);
  float* part    =(float*)(wsb+off_part);
  bf16*  Bm      =(bf16*)(wsb+off_B);

  k_init_cg<<<NTRI,64,0,stream>>>(cg, cm);
  int tiles=gm.tb[6];
  if (nb==NB){
    k_mid3<<<dim3(NTRI*3,NB),192,0,stream>>>(act,cg,Bm,partial,mp,0);
    k_scale<<<(MS_LEN+255)/256,256,0,stream>>>(partial,mstd,scale,gm);
    k_buildA<<<(W_CPLX+255)/256,256,0,stream>>>(wts,scale,Am,gm);
    k_gemm2<<<dim3(tiles,4),256,0,stream>>>(Am,Bm,part,gm);
    k_red<<<tiles,256,0,stream>>>(part,outf,gm,0);
  } else {
    for (int b0=0;b0<NB;b0+=nb)
      k_mid3<<<dim3(NTRI*3,nb),192,0,stream>>>(act,cg,Bm,partial,mp,b0);
    k_scale<<<(MS_LEN+255)/256,256,0,stream>>>(partial,mstd,scale,gm);
    k_buildA<<<(W_CPLX+255)/256,256,0,stream>>>(wts,scale,Am,gm);
    for (int b0=0;b0<NB;b0+=nb){
      k_mid3<<<dim3(NTRI*3,nb),192,0,stream>>>(act,cg,Bm,partial,mp,b0);
      k_gemm2<<<dim3(tiles,4),256,0,stream>>>(Am,Bm,part,gm);
      k_red<<<tiles,256,0,stream>>>(part,outf,gm,b0);
    }
  }
}